// Round 2
// baseline (2508.919 us; speedup 1.0000x reference)
//
#include <hip/hip_runtime.h>

#define NPTS   16384
#define KCODES 8192
#define DDIM   256
#define HWSZ   1024
#define CHW    (DDIM * HWSZ)          // 262144
#define OUT_ELEMS 4194304
#define LOSS_OFF  OUT_ELEMS
#define IDX_OFF   (OUT_ELEMS + 1)

#define PT 32            // points per block
#define KT 512           // codes per pass
#define DK 16            // d-chunk staged in LDS
#define NPASS  (KCODES / KT)   // 16
#define NCHUNK (DDIM / DK)     // 16
#define NITER  (NPASS * NCHUNK) // 256
#define XLD (DDIM + 4)   // 260 floats: x row pitch (16B-aligned, breaks col conflicts)
#define RPITCH 33        // reduce-array pitch

// swizzle: element (d,k) of e-chunk lives at pool[d*KT + ((((k>>2) ^ SW(d)) << 2) | (k&3))]
#define SW(d) (((d) & 7) ^ ((d) >> 3))

__launch_bounds__(256, 2)
__global__ void vq_kernel(const float* __restrict__ x,
                          const float* __restrict__ emb,
                          float* __restrict__ out)
{
    __shared__ float  ldsX[PT][XLD];     // 33280 B: x tile, full D
    __shared__ float  ldsPool[DK * KT];  // 32768 B: e chunk (swizzled transpose); later argmin reduce
    __shared__ float  ldsSE[KT];         // 2048 B: ||e||^2 per code of current pass
    __shared__ float  ldsS[PT];
    __shared__ int    ldsI[PT];
    __shared__ double ldsL[4];

    const int t   = threadIdx.x;
    const int n0  = blockIdx.x * PT;
    const int b   = n0 / HWSZ;
    const int hw0 = n0 % HWSZ;
    const float* xbase = x + (size_t)b * CHW + hw0;

    const int kq  = t >> 2;          // staging code base (0..63), +i*64
    const int dq4 = (t & 3) * 4;     // staging d offset {0,4,8,12}

    // ---- prefetch chunk 0 of pass 0 (overlaps x staging) ----
    float4 stg[8];
    {
        const float* src = emb + (size_t)kq * DDIM + dq4;
        #pragma unroll
        for (int i = 0; i < 8; ++i)
            stg[i] = *(const float4*)(src + (size_t)i * 64 * DDIM);
    }

    // ---- stage x tile: ldsX[p][c] = x[b][c][hw0+p]; zero ldsSE ----
    {
        const int p  = t & 31;
        const int c0 = t >> 5;
        for (int i = 0; i < 32; ++i) {
            const int c = c0 * 32 + i;
            ldsX[p][c] = xbase[(size_t)c * HWSZ + p];
        }
    }
    ldsSE[t] = 0.0f;
    ldsSE[t + 256] = 0.0f;
    __syncthreads();

    // ---- s[p] = ||x_p||^2 (fp32 FMA; constant-per-point error cancels in argmin) ----
    {
        const int p   = t & 31;
        const int seg = t >> 5;
        float a = 0.0f;
        for (int i = 0; i < 32; ++i) { float v = ldsX[p][seg * 32 + i]; a = fmaf(v, v, a); }
        ldsPool[seg * RPITCH + p] = a;
    }
    __syncthreads();
    if (t < PT) {
        float s = 0.0f;
        for (int g = 0; g < 8; ++g) s += ldsPool[g * RPITCH + t];
        ldsS[t] = s;
    }
    __syncthreads();

    const int kg = t & 63;           // code-group: codes 4kg..4kg+3 (L) and +256 (H)
    const int p0 = (t >> 6) * 8;     // point-group: 8 points

    float s_reg[8];
    #pragma unroll
    for (int i = 0; i < 8; ++i) s_reg[i] = ldsS[p0 + i];

    float best_d[8];
    int   best_i[8];
    #pragma unroll
    for (int i = 0; i < 8; ++i) { best_d[i] = 3.4e38f; best_i[i] = 0; }

    for (int kp = 0; kp < NPASS; ++kp) {
        const int kbase = kp * KT;
        float4 accL[8], accH[8];
        #pragma unroll
        for (int i = 0; i < 8; ++i) {
            accL[i] = make_float4(0.f, 0.f, 0.f, 0.f);
            accH[i] = make_float4(0.f, 0.f, 0.f, 0.f);
        }

        for (int ch = 0; ch < NCHUNK; ++ch) {
            __syncthreads();   // prior readers of pool done; SE zero visible
            // ---- write prefetched e chunk into swizzled transpose; SE partials ----
            #pragma unroll
            for (int i = 0; i < 8; ++i) {
                const int k   = kq + i * 64;       // local code 0..511
                const int kg2 = k >> 2;
                const int km  = k & 3;
                const float4 v = stg[i];
                #pragma unroll
                for (int j = 0; j < 4; ++j) {
                    const int d = dq4 + j;
                    ldsPool[d * KT + (((kg2 ^ SW(d)) << 2) | km)] = ((const float*)&v)[j];
                }
                // ||e||^2 partial: this thread holds d-range dq4..dq4+3 of code k
                float ps = v.x * v.x;
                ps = fmaf(v.y, v.y, ps);
                ps = fmaf(v.z, v.z, ps);
                ps = fmaf(v.w, v.w, ps);
                ps += __shfl_xor(ps, 1);
                ps += __shfl_xor(ps, 2);
                if ((t & 3) == 0) ldsSE[k] += ps;  // single writer per code
            }
            __syncthreads();   // e tile + SE partial ready
            // ---- prefetch next chunk (in flight across the FMA block) ----
            {
                int nit = kp * NCHUNK + ch + 1;
                if (nit == NITER) nit = 0;         // harmless dummy
                const int nkp = nit >> 4, nch = nit & 15;
                const float* src = emb + ((size_t)(nkp * KT + kq) * DDIM) + nch * DK + dq4;
                #pragma unroll
                for (int i = 0; i < 8; ++i)
                    stg[i] = *(const float4*)(src + (size_t)i * 64 * DDIM);
            }
            // ---- FMA: 8 points x 8 codes, 16 d ----
            #pragma unroll
            for (int cb = 0; cb < 4; ++cb) {
                float4 xv[8];
                #pragma unroll
                for (int p = 0; p < 8; ++p)        // wave-uniform address -> LDS broadcast
                    xv[p] = *(const float4*)&ldsX[p0 + p][ch * DK + cb * 4];
                #pragma unroll
                for (int dd = 0; dd < 4; ++dd) {
                    const int d  = cb * 4 + dd;
                    const int go = (kg ^ SW(d)) << 2;
                    const float4 eL = *(const float4*)&ldsPool[d * KT + go];
                    const float4 eH = *(const float4*)&ldsPool[d * KT + go + 256];
                    #pragma unroll
                    for (int p = 0; p < 8; ++p) {
                        const float xs = ((const float*)&xv[p])[dd];
                        accL[p].x = fmaf(xs, eL.x, accL[p].x);
                        accL[p].y = fmaf(xs, eL.y, accL[p].y);
                        accL[p].z = fmaf(xs, eL.z, accL[p].z);
                        accL[p].w = fmaf(xs, eL.w, accL[p].w);
                        accH[p].x = fmaf(xs, eH.x, accH[p].x);
                        accH[p].y = fmaf(xs, eH.y, accH[p].y);
                        accH[p].z = fmaf(xs, eH.z, accH[p].z);
                        accH[p].w = fmaf(xs, eH.w, accH[p].w);
                    }
                }
            }
        }
        // SE stable since last mid-chunk barrier; finalize dist = fl(fl(s+se) - 2m)
        #pragma unroll
        for (int j = 0; j < 4; ++j) {            // L half first (smaller indices)
            const float se = ldsSE[4 * kg + j];
            const int   ki = kbase + 4 * kg + j;
            #pragma unroll
            for (int i = 0; i < 8; ++i) {
                const float T = s_reg[i] + se;
                const float d = fmaf(-2.0f, ((const float*)&accL[i])[j], T);
                if (d < best_d[i]) { best_d[i] = d; best_i[i] = ki; }
            }
        }
        #pragma unroll
        for (int j = 0; j < 4; ++j) {            // H half
            const float se = ldsSE[256 + 4 * kg + j];
            const int   ki = kbase + 256 + 4 * kg + j;
            #pragma unroll
            for (int i = 0; i < 8; ++i) {
                const float T = s_reg[i] + se;
                const float d = fmaf(-2.0f, ((const float*)&accH[i])[j], T);
                if (d < best_d[i]) { best_d[i] = d; best_i[i] = ki; }
            }
        }
        __syncthreads();   // finalize reads done
        ldsSE[t] = 0.0f;
        ldsSE[t + 256] = 0.0f;
    }

    // ---- cross-thread argmin (lexicographic: dist, then index) via pool overlay ----
    {
        float* ldsRD = ldsPool;                       // [64][RPITCH]
        int*   ldsRI = (int*)&ldsPool[64 * RPITCH];   // [64][RPITCH]
        #pragma unroll
        for (int i = 0; i < 8; ++i) {
            ldsRD[kg * RPITCH + p0 + i] = best_d[i];
            ldsRI[kg * RPITCH + p0 + i] = best_i[i];
        }
        __syncthreads();
        if (t < PT) {
            float bd = ldsRD[t];
            int   bi = ldsRI[t];
            for (int g = 1; g < 64; ++g) {
                const float d2 = ldsRD[g * RPITCH + t];
                const int   i2 = ldsRI[g * RPITCH + t];
                if (d2 < bd || (d2 == bd && i2 < bi)) { bd = d2; bi = i2; }
            }
            ldsI[t] = bi;
            out[(size_t)IDX_OFF + n0 + t] = (float)bi;
        }
    }
    __syncthreads();

    // ---- gather x_q, straight-through out, loss partial ----
    double lsum = 0.0;
    {
        const int p  = t & 31;
        const int cg = t >> 5;
        const int row = ldsI[p];
        const float* erow = emb + (size_t)row * DDIM;
        float* obase = out + (size_t)b * CHW + hw0 + p;
        for (int q = 0; q < 8; ++q) {
            const int c = cg * 32 + q * 4;
            const float4 ev = *(const float4*)(erow + c);
            const float4 xv = *(const float4*)&ldsX[p][c];
            #pragma unroll
            for (int u = 0; u < 4; ++u) {
                const float e  = ((const float*)&ev)[u];
                const float xx = ((const float*)&xv)[u];
                const float diff = e - xx;
                obase[(size_t)(c + u) * HWSZ] = xx + diff;  // replicate straight-through rounding
                lsum += (double)diff * (double)diff;
            }
        }
    }
    #pragma unroll
    for (int off = 32; off > 0; off >>= 1)
        lsum += __shfl_xor(lsum, off);
    if ((t & 63) == 0) ldsL[t >> 6] = lsum;
    __syncthreads();
    if (t == 0) {
        const double tot = ldsL[0] + ldsL[1] + ldsL[2] + ldsL[3];
        atomicAdd(&out[LOSS_OFF], (float)(tot * (1.25 / 4194304.0)));
    }
}

extern "C" void kernel_launch(void* const* d_in, const int* in_sizes, int n_in,
                              void* d_out, int out_size, void* d_ws, size_t ws_size,
                              hipStream_t stream) {
    (void)in_sizes; (void)n_in; (void)ws_size; (void)d_ws; (void)out_size;
    const float* x   = (const float*)d_in[0];
    const float* emb = (const float*)d_in[1];
    float* out = (float*)d_out;
    hipMemsetAsync((char*)d_out + (size_t)LOSS_OFF * sizeof(float), 0, sizeof(float), stream);
    vq_kernel<<<NPTS / PT, 256, 0, stream>>>(x, emb, out);
}

// Round 3
// 994.568 us; speedup vs baseline: 2.5226x; 2.5226x over previous
//
#include <hip/hip_runtime.h>

#define NPTS   16384
#define KCODES 8192
#define DDIM   256
#define HWSZ   1024
#define CHW    (DDIM * HWSZ)          // 262144
#define OUT_ELEMS 4194304
#define LOSS_OFF  OUT_ELEMS
#define IDX_OFF   (OUT_ELEMS + 1)

#define PT 32            // points per block
#define KT 512           // codes per pass
#define DK 8             // d-chunk staged in LDS
#define NPASS  (KCODES / KT)    // 16
#define NCHUNK (DDIM / DK)      // 32
#define NITER  (NPASS * NCHUNK) // 512

// swizzled transposed e-tile: element (d, k) -> pool[d*KT + ((((k>>2) ^ d) << 2) | (k&3))]
// staging writes land 2-way per bank (free); FMA reads conflict-light.

__launch_bounds__(256)
__global__ void vq_kernel(const float* __restrict__ x,
                          const float* __restrict__ emb,
                          float* __restrict__ out)
{
    __shared__ float  pool[DK * KT];     // 16384 B: e chunk, swizzled transpose
    __shared__ float  ldsSE[KT];         // 2048 B: ||e||^2 per code of current pass
    __shared__ float  ldsRD[64 * 33];    // 8448 B: argmin reduce dist (pitch 33)
    __shared__ int    ldsRI[64 * 33];    // 8448 B: argmin reduce idx
    __shared__ float  ldsS[PT];
    __shared__ int    ldsI[PT];
    __shared__ double ldsL[4];

    const int t   = threadIdx.x;
    const int n0  = blockIdx.x * PT;
    const int b   = n0 / HWSZ;
    const int hw0 = n0 % HWSZ;
    const float* xs = x + (size_t)b * CHW + hw0;   // xs[c*HWSZ + p] = x[b][c][hw0+p]

    const int kq = t >> 1;          // staging code base (0..127), +128*i
    const int dh = (t & 1) * 4;     // staging d-half offset {0,4}

    // ---- prefetch e chunk 0 of pass 0 ----
    float4 stg[4];
    {
        const float* src = emb + (size_t)kq * DDIM + dh;
        #pragma unroll
        for (int i = 0; i < 4; ++i)
            stg[i] = *(const float4*)(src + (size_t)i * 128 * DDIM);
    }

    // ---- prologue: s[p] = ||x_p||^2 (fp32 FMA; constant-per-point error cancels in argmin) ----
    {
        const int p   = t & 31;
        const int seg = t >> 5;
        float a = 0.0f;
        for (int i = 0; i < 32; ++i) {
            const float v = xs[(size_t)(seg * 32 + i) * HWSZ + p];
            a = fmaf(v, v, a);
        }
        ldsRD[seg * 33 + p] = a;
    }
    ldsSE[t] = 0.0f;
    ldsSE[t + 256] = 0.0f;
    __syncthreads();
    if (t < PT) {
        float s = 0.0f;
        for (int g = 0; g < 8; ++g) s += ldsRD[g * 33 + t];
        ldsS[t] = s;
    }
    __syncthreads();

    const int kg = t & 63;                         // codes 4kg..4kg+3 (L) and +256 (H)
    const int p0 = (t >> 6) * 8;                   // 8 points per thread
    const int p0u = __builtin_amdgcn_readfirstlane(p0);
    const float* xu = xs + p0u;                    // wave-uniform x base

    float best_d[8];
    int   best_i[8];
    #pragma unroll
    for (int i = 0; i < 8; ++i) { best_d[i] = 3.4e38f; best_i[i] = 0; }

    for (int kp = 0; kp < NPASS; ++kp) {
        const int kbase = kp * KT;
        float4 accL[8], accH[8];
        #pragma unroll
        for (int i = 0; i < 8; ++i) {
            accL[i] = make_float4(0.f, 0.f, 0.f, 0.f);
            accH[i] = make_float4(0.f, 0.f, 0.f, 0.f);
        }

        for (int ch = 0; ch < NCHUNK; ++ch) {
            __syncthreads();   // prior readers of pool done; SE state settled
            // ---- write prefetched e chunk into swizzled transpose; SE partials ----
            #pragma unroll
            for (int i = 0; i < 4; ++i) {
                const int k = kq + 128 * i;        // local code 0..511
                const int g = k >> 2;
                const int m = k & 3;
                const float4 v = stg[i];
                #pragma unroll
                for (int j = 0; j < 4; ++j) {
                    const int d = dh + j;
                    pool[d * KT + (((g ^ d) << 2) | m)] = ((const float*)&v)[j];
                }
                float ps = v.x * v.x;
                ps = fmaf(v.y, v.y, ps);
                ps = fmaf(v.z, v.z, ps);
                ps = fmaf(v.w, v.w, ps);
                ps += __shfl_xor(ps, 1);           // combine the two d-halves
                if ((t & 1) == 0) ldsSE[k] += ps;  // single writer, banks distinct
            }
            __syncthreads();   // e tile + SE ready
            // ---- prefetch next chunk (small reg footprint, in flight across FMA) ----
            {
                int nit = kp * NCHUNK + ch + 1;
                if (nit == NITER) nit = 0;         // harmless dummy
                const int nkp = nit >> 5, nch = nit & 31;
                const float* src = emb + ((size_t)(nkp * KT + kq) * DDIM) + nch * DK + dh;
                #pragma unroll
                for (int i = 0; i < 4; ++i)
                    stg[i] = *(const float4*)(src + (size_t)i * 128 * DDIM);
            }
            // ---- FMA: 8 points x 8 codes x 8 d; x via wave-uniform global reads ----
            #pragma unroll
            for (int cb = 0; cb < 2; ++cb) {
                #pragma unroll
                for (int dd = 0; dd < 4; ++dd) {
                    const int ld = cb * 4 + dd;    // local d 0..7
                    const int c  = ch * DK + ld;   // global channel
                    const int go = (kg ^ ld) << 2;
                    const float4 eL = *(const float4*)&pool[ld * KT + go];
                    const float4 eH = *(const float4*)&pool[ld * KT + go + 256];
                    #pragma unroll
                    for (int p = 0; p < 8; ++p) {
                        const float xsc = xu[(size_t)c * HWSZ + p];  // uniform -> broadcast
                        accL[p].x = fmaf(xsc, eL.x, accL[p].x);
                        accL[p].y = fmaf(xsc, eL.y, accL[p].y);
                        accL[p].z = fmaf(xsc, eL.z, accL[p].z);
                        accL[p].w = fmaf(xsc, eL.w, accL[p].w);
                        accH[p].x = fmaf(xsc, eH.x, accH[p].x);
                        accH[p].y = fmaf(xsc, eH.y, accH[p].y);
                        accH[p].z = fmaf(xsc, eH.z, accH[p].z);
                        accH[p].w = fmaf(xsc, eH.w, accH[p].w);
                    }
                }
            }
        }
        // ---- finalize pass: dist = fl(fl(s+se) - 2m), ascending code index ----
        #pragma unroll
        for (int j = 0; j < 4; ++j) {              // L half first (smaller indices)
            const float se = ldsSE[4 * kg + j];
            const int   ki = kbase + 4 * kg + j;
            #pragma unroll
            for (int i = 0; i < 8; ++i) {
                const float T = ldsS[p0 + i] + se;
                const float d = fmaf(-2.0f, ((const float*)&accL[i])[j], T);
                if (d < best_d[i]) { best_d[i] = d; best_i[i] = ki; }
            }
        }
        #pragma unroll
        for (int j = 0; j < 4; ++j) {              // H half
            const float se = ldsSE[256 + 4 * kg + j];
            const int   ki = kbase + 256 + 4 * kg + j;
            #pragma unroll
            for (int i = 0; i < 8; ++i) {
                const float T = ldsS[p0 + i] + se;
                const float d = fmaf(-2.0f, ((const float*)&accH[i])[j], T);
                if (d < best_d[i]) { best_d[i] = d; best_i[i] = ki; }
            }
        }
        __syncthreads();   // finalize reads done before re-zero
        ldsSE[t] = 0.0f;
        ldsSE[t + 256] = 0.0f;
    }

    // ---- cross-thread argmin (lexicographic: dist, then index) ----
    #pragma unroll
    for (int i = 0; i < 8; ++i) {
        ldsRD[kg * 33 + p0 + i] = best_d[i];
        ldsRI[kg * 33 + p0 + i] = best_i[i];
    }
    __syncthreads();
    if (t < PT) {
        float bd = ldsRD[t];
        int   bi = ldsRI[t];
        for (int g = 1; g < 64; ++g) {
            const float d2 = ldsRD[g * 33 + t];
            const int   i2 = ldsRI[g * 33 + t];
            if (d2 < bd || (d2 == bd && i2 < bi)) { bd = d2; bi = i2; }
        }
        ldsI[t] = bi;
        out[(size_t)IDX_OFF + n0 + t] = (float)bi;
    }
    __syncthreads();

    // ---- epilogue: gather e row, straight-through out, loss partial ----
    double lsum = 0.0;
    {
        const int p  = t & 31;
        const int cg = t >> 5;
        const int row = ldsI[p];
        const float* erow = emb + (size_t)row * DDIM;
        float* ob = out + (size_t)b * CHW + hw0 + p;
        for (int q = 0; q < 32; ++q) {
            const int c = cg * 32 + q;
            const float e  = erow[c];                      // gather (L2/L3-hot)
            const float xx = xs[(size_t)c * HWSZ + p];     // coalesced across lanes
            const float diff = e - xx;                     // fl(x_q - xt)
            ob[(size_t)c * HWSZ] = xx + diff;              // straight-through rounding
            lsum += (double)diff * (double)diff;
        }
    }
    #pragma unroll
    for (int off = 32; off > 0; off >>= 1)
        lsum += __shfl_xor(lsum, off);
    if ((t & 63) == 0) ldsL[t >> 6] = lsum;
    __syncthreads();
    if (t == 0) {
        const double tot = ldsL[0] + ldsL[1] + ldsL[2] + ldsL[3];
        atomicAdd(&out[LOSS_OFF], (float)(tot * (1.25 / 4194304.0)));
    }
}

extern "C" void kernel_launch(void* const* d_in, const int* in_sizes, int n_in,
                              void* d_out, int out_size, void* d_ws, size_t ws_size,
                              hipStream_t stream) {
    (void)in_sizes; (void)n_in; (void)ws_size; (void)d_ws; (void)out_size;
    const float* x   = (const float*)d_in[0];
    const float* emb = (const float*)d_in[1];
    float* out = (float*)d_out;
    hipMemsetAsync((char*)d_out + (size_t)LOSS_OFF * sizeof(float), 0, sizeof(float), stream);
    vq_kernel<<<NPTS / PT, 256, 0, stream>>>(x, emb, out);
}